// Round 4
// baseline (196.817 us; speedup 1.0000x reference)
//
#include <hip/hip_runtime.h>
#include <hip/hip_bf16.h>
#include <math.h>

// Problem constants (reference: B=2, T=2048, D_MODEL=1024, N_HEAD=16, D_HEAD=64)
constexpr int Bb   = 2;
constexpr int T    = 2048;
constexpr int C    = 1024;
constexpr int H    = 16;
constexpr int M    = Bb * T;   // 4096 rows
constexpr int NQKV = 3 * C;    // 3072

typedef __attribute__((ext_vector_type(8))) short bf16x8;
typedef __attribute__((ext_vector_type(4))) float f32x4;
typedef __attribute__((ext_vector_type(16))) float f32x16;

__device__ inline short f2bf(float f) {
    __hip_bfloat16 h = __float2bfloat16(f);
    return *reinterpret_cast<short*>(&h);
}

#if __has_builtin(__builtin_amdgcn_exp2f)
#define EXP2(x) __builtin_amdgcn_exp2f(x)
#else
#define EXP2(x) exp2f(x)
#endif

#define GLOBAL_AS __attribute__((address_space(1)))
#define LDS_AS    __attribute__((address_space(3)))

__device__ __forceinline__ void gload_lds16(const short* g, short* s) {
    __builtin_amdgcn_global_load_lds((const GLOBAL_AS void*)g, (LDS_AS void*)s, 16, 0, 0);
}

// ---------------------------------------------------------------------------
// Fused prep: x->bf16 (blocks 0..4095), w_qkv transpose (4096..7167),
// w_proj transpose (7168..8191). Unchanged.
// ---------------------------------------------------------------------------
__global__ __launch_bounds__(256)
void prep_all(const float* __restrict__ x, short* __restrict__ xb,
              const float* __restrict__ w_qkv, short* __restrict__ wqkvt,
              const float* __restrict__ w_proj, short* __restrict__ wprojt)
{
    __shared__ float tile[32][33];
    const int blk = blockIdx.x;
    const int tid = threadIdx.x;

    if (blk < 4096) {                       // cvt x
        const int i = blk * 1024 + tid * 4;
        const float4 v = *(const float4*)(x + i);
        short4 s;
        s.x = f2bf(v.x); s.y = f2bf(v.y); s.z = f2bf(v.z); s.w = f2bf(v.w);
        *(short4*)(xb + i) = s;
        return;
    }

    const bool isqkv = (blk < 7168);
    const int bidx = isqkv ? (blk - 4096) : (blk - 7168);
    const int nblk = isqkv ? 96 : 32;       // N/32
    const int N    = isqkv ? NQKV : C;
    const float* W = isqkv ? w_qkv : w_proj;
    short* Wt      = isqkv ? wqkvt : wprojt;

    const int n0 = (bidx % nblk) * 32, k0 = (bidx / nblk) * 32;
    const int tx = tid & 31, ty = tid >> 5;   // 32 x 8
#pragma unroll
    for (int i = 0; i < 32; i += 8)
        tile[ty + i][tx] = W[(size_t)(k0 + ty + i) * N + n0 + tx];
    __syncthreads();
#pragma unroll
    for (int i = 0; i < 32; i += 8)
        Wt[(size_t)(n0 + ty + i) * C + k0 + tx] = f2bf(tile[tx][ty + i]);
}

// ---------------------------------------------------------------------------
// QKV GEMM: 128x128 tile, BK=32, 2-phase prefetch double-buffer + XCD swizzle.
// Unchanged from R1.
// ---------------------------------------------------------------------------
__global__ __launch_bounds__(256)
void gemm_mfma(const short* __restrict__ A, const short* __restrict__ Bt,
               const float* __restrict__ bias, short* __restrict__ outp,
               int Ndim, int Kdim)
{
    __shared__ __align__(16) short As[2 * 128 * 32];   // 16 KB (double-buffered)
    __shared__ __align__(16) short Bs[2 * 128 * 32];   // 16 KB

    const int tid = threadIdx.x;
    const int w   = tid >> 6;
    const int l   = tid & 63;
    const int lk  = l & 15;
    const int lq  = l >> 4;

    const int gx  = gridDim.x;
    const int nwg = gx * gridDim.y;          // 768, divisible by 8
    const int cpx = nwg >> 3;
    const int bid = blockIdx.y * gx + blockIdx.x;
    const int swz = (bid & 7) * cpx + (bid >> 3);
    const int m0  = (swz / gx) * 128;
    const int n0  = (swz % gx) * 128;

    const int mw  = (w >> 1) * 64, nw = (w & 1) * 64;

    const int srow = w * 16 + (l >> 2);
    const int scol = (l & 3) * 8;

    const short* agp0 = A  + (size_t)(m0 + srow)      * Kdim + scol;
    const short* agp1 = A  + (size_t)(m0 + 64 + srow) * Kdim + scol;
    const short* bgp0 = Bt + (size_t)(n0 + srow)      * Kdim + scol;
    const short* bgp1 = Bt + (size_t)(n0 + 64 + srow) * Kdim + scol;

    short* ad0 = &As[w * 512];
    short* ad1 = &As[2048 + w * 512];
    short* bd0 = &Bs[w * 512];
    short* bd1 = &Bs[2048 + w * 512];

    f32x4 acc[4][4];
#pragma unroll
    for (int i = 0; i < 4; ++i)
#pragma unroll
        for (int j = 0; j < 4; ++j) acc[i][j] = (f32x4){0.f, 0.f, 0.f, 0.f};

    gload_lds16(agp0, ad0);
    gload_lds16(agp1, ad1);
    gload_lds16(bgp0, bd0);
    gload_lds16(bgp1, bd1);
    __syncthreads();

    int cur = 0;
    for (int k0 = 0; k0 < Kdim; k0 += 32) {
        const int coff = cur ? 4096 : 0;

        bf16x8 af[4], bfr[4];
#pragma unroll
        for (int mt = 0; mt < 4; ++mt)
            af[mt] = *(const bf16x8*)&As[coff + (mw + mt * 16 + lk) * 32 + lq * 8];
#pragma unroll
        for (int nt = 0; nt < 4; ++nt)
            bfr[nt] = *(const bf16x8*)&Bs[coff + (nw + nt * 16 + lk) * 32 + lq * 8];

        if (k0 + 32 < Kdim) {
            const int noff = cur ? 0 : 4096;
            gload_lds16(agp0 + k0 + 32, ad0 + noff);
            gload_lds16(agp1 + k0 + 32, ad1 + noff);
            gload_lds16(bgp0 + k0 + 32, bd0 + noff);
            gload_lds16(bgp1 + k0 + 32, bd1 + noff);
        }

#pragma unroll
        for (int mt = 0; mt < 4; ++mt)
#pragma unroll
            for (int nt = 0; nt < 4; ++nt)
                acc[mt][nt] = __builtin_amdgcn_mfma_f32_16x16x32_bf16(bfr[nt], af[mt], acc[mt][nt], 0, 0, 0);

        __syncthreads();
        cur ^= 1;
    }

    float4 bv[4];
#pragma unroll
    for (int nt = 0; nt < 4; ++nt)
        bv[nt] = *(const float4*)(bias + n0 + nw + nt * 16 + lq * 4);
#pragma unroll
    for (int mt = 0; mt < 4; ++mt) {
        short* rowp = outp + (size_t)(m0 + mw + mt * 16 + lk) * Ndim + n0 + nw + lq * 4;
#pragma unroll
        for (int nt = 0; nt < 4; ++nt) {
            short4 pk;
            pk.x = f2bf(acc[mt][nt][0] + bv[nt].x);
            pk.y = f2bf(acc[mt][nt][1] + bv[nt].y);
            pk.z = f2bf(acc[mt][nt][2] + bv[nt].z);
            pk.w = f2bf(acc[mt][nt][3] + bv[nt].w);
            *(short4*)(rowp + nt * 16) = pk;
        }
    }
}

// ---------------------------------------------------------------------------
// Proj GEMM: 64x128 tile, BK=32, 2-phase prefetch + XCD swizzle. Unchanged.
// ---------------------------------------------------------------------------
__global__ __launch_bounds__(256)
void gemm_mfma_proj(const short* __restrict__ A, const short* __restrict__ Bt,
                    const float* __restrict__ bias, float* __restrict__ outp,
                    int Ndim, int Kdim)
{
    __shared__ __align__(16) short As[2 * 64 * 32];    //  8 KB
    __shared__ __align__(16) short Bs[2 * 128 * 32];   // 16 KB

    const int tid = threadIdx.x;
    const int w   = tid >> 6;
    const int l   = tid & 63;
    const int lk  = l & 15;
    const int lq  = l >> 4;

    const int gx  = gridDim.x;
    const int nwg = gx * gridDim.y;          // 512, divisible by 8
    const int cpx = nwg >> 3;
    const int bid = blockIdx.y * gx + blockIdx.x;
    const int swz = (bid & 7) * cpx + (bid >> 3);
    const int m0  = (swz / gx) * 64;
    const int n0  = (swz % gx) * 128;

    const int mw  = (w & 1) * 32, nw = (w >> 1) * 64;

    const int srow = w * 16 + (l >> 2);
    const int scol = (l & 3) * 8;

    const short* agp  = A  + (size_t)(m0 + srow)      * Kdim + scol;
    const short* bgp0 = Bt + (size_t)(n0 + srow)      * Kdim + scol;
    const short* bgp1 = Bt + (size_t)(n0 + 64 + srow) * Kdim + scol;

    short* ad  = &As[w * 512];
    short* bd0 = &Bs[w * 512];
    short* bd1 = &Bs[2048 + w * 512];

    f32x4 acc[2][4];
#pragma unroll
    for (int i = 0; i < 2; ++i)
#pragma unroll
        for (int j = 0; j < 4; ++j) acc[i][j] = (f32x4){0.f, 0.f, 0.f, 0.f};

    gload_lds16(agp,  ad);
    gload_lds16(bgp0, bd0);
    gload_lds16(bgp1, bd1);
    __syncthreads();

    int cur = 0;
    for (int k0 = 0; k0 < Kdim; k0 += 32) {
        const int coffA = cur ? 2048 : 0;
        const int coffB = cur ? 4096 : 0;

        bf16x8 af[2], bfr[4];
#pragma unroll
        for (int mt = 0; mt < 2; ++mt)
            af[mt] = *(const bf16x8*)&As[coffA + (mw + mt * 16 + lk) * 32 + lq * 8];
#pragma unroll
        for (int nt = 0; nt < 4; ++nt)
            bfr[nt] = *(const bf16x8*)&Bs[coffB + (nw + nt * 16 + lk) * 32 + lq * 8];

        if (k0 + 32 < Kdim) {
            const int noffA = cur ? 0 : 2048;
            const int noffB = cur ? 0 : 4096;
            gload_lds16(agp  + k0 + 32, ad  + noffA);
            gload_lds16(bgp0 + k0 + 32, bd0 + noffB);
            gload_lds16(bgp1 + k0 + 32, bd1 + noffB);
        }

#pragma unroll
        for (int mt = 0; mt < 2; ++mt)
#pragma unroll
            for (int nt = 0; nt < 4; ++nt)
                acc[mt][nt] = __builtin_amdgcn_mfma_f32_16x16x32_bf16(bfr[nt], af[mt], acc[mt][nt], 0, 0, 0);

        __syncthreads();
        cur ^= 1;
    }

    float4 bv[4];
#pragma unroll
    for (int nt = 0; nt < 4; ++nt)
        bv[nt] = *(const float4*)(bias + n0 + nw + nt * 16 + lq * 4);
#pragma unroll
    for (int mt = 0; mt < 2; ++mt) {
        float* rowp = outp + (size_t)(m0 + mw + mt * 16 + lk) * Ndim + n0 + nw + lq * 4;
#pragma unroll
        for (int nt = 0; nt < 4; ++nt) {
            float4 v;
            v.x = acc[mt][nt][0] + bv[nt].x;
            v.y = acc[mt][nt][1] + bv[nt].y;
            v.z = acc[mt][nt][2] + bv[nt].z;
            v.w = acc[mt][nt][3] + bv[nt].w;
            *(float4*)(rowp + nt * 16) = v;
        }
    }
}

// ---------------------------------------------------------------------------
// MFMA flash attention v11: 32x32x16 MFMA -- halves LDS read traffic/q-row.
//  - 512 blocks x 4 waves; wave owns 32 q-rows (128/block); KVBLK=128.
//  - K+V double-buffered (64 KB, 2 blocks/CU, all 512 co-resident), one
//    barrier/tile, K prefetch via gload_lds + V via regs issued pre-compute.
//  - S^T = K Q^T with C col=q: 64 of 128 key-scores live in-thread ->
//    softmax reduce = in-thread tree + ONE shfl_xor(32).
//  - PV slot-permuted Vt: P^T feeds the MFMA B-operand straight from QK^T
//    output regs (key<->slot maps of A and B agree; contraction-order
//    permutation cancels). key kk -> pos (kk&3)+4*((kk>>3)&1)+8*((kk>>2)&1)
//    +16*((kk>>4)&1)+32*(kk>>5); granule XOR d&15 for bank spread.
//  - Deferred l-sum: per-thread lacc rescaled by corr; 1 shfl at epilogue.
// ---------------------------------------------------------------------------
constexpr float SC = 0.18033688f;   // 0.125 * log2(e)

__global__ __launch_bounds__(256, 2)
void attn_mfma(const short* __restrict__ qkv, short* __restrict__ att)
{
    __shared__ __align__(16) short Ks[2][128 * 64];   // 2x16 KB, granule^row&7
    __shared__ __align__(16) short Vt[2][64 * 128];   // 2x16 KB, slot-permuted

    const int idx  = blockIdx.x;         // 0..511
    const int half = idx >> 8;
    const int i    = idx & 255;
    const int xcd  = i & 7;
    const int bh   = xcd * 4 + ((i >> 3) & 3);
    const int s    = i >> 5;             // 0..7
    const int qt   = half ? (15 - s) : s;
    const int b    = bh >> 4;
    const int h    = bh & 15;
    const int qbase = qt * 128;
    const int nkt   = qt + 1;

    const int tid = threadIdx.x;
    const int w   = tid >> 6;            // 0..3
    const int l   = tid & 63;
    const int c31 = l & 31;
    const int hi  = l >> 5;

    const short* base = qkv + (size_t)b * T * 3072 + h * 64;

    // Q fragments (B-operand): lane owns q-col q_abs; k-rows hi*8+j at d-step
    const int q_abs = qbase + w * 32 + c31;
    const short* qp = base + (size_t)q_abs * 3072 + hi * 8;
    bf16x8 qf[4];
#pragma unroll
    for (int ds = 0; ds < 4; ++ds)
        qf[ds] = *(const bf16x8*)(qp + ds * 16);

    f32x16 acc_o[2];
#pragma unroll
    for (int dt = 0; dt < 2; ++dt)
#pragma unroll
        for (int r = 0; r < 16; ++r) acc_o[dt][r] = 0.f;
    float m_run = -INFINITY;
    float lacc  = 0.f;

    // K staging: per-thread granule (l&7) of row (l>>3), source col XOR'd
    const int kswz = 8 * ((l & 7) ^ ((l >> 3) & 7));

    // V staging: thread owns keys {2l, 2l+1}, dims w*16 .. +15
    const int k0v = 2 * l;
    const int kk5 = k0v & 31;
    const int pos = (k0v >> 5) * 32 + ((kk5 >> 4) & 1) * 16 + ((kk5 >> 2) & 1) * 8
                  + ((kk5 >> 3) & 1) * 4 + (kk5 & 3);   // even
    const int vg  = pos >> 3;
    const int vpo = pos & 7;
    const int seg = w * 16;

    union { uint4 q[2]; unsigned int u[8]; } KA, KB;
    const int dmask = c31 & 15;          // Vt read swizzle source

    // ---- prologue: stage tile 0 into buffer 0 ----
#pragma unroll
    for (int rr = 0; rr < 4; ++rr) {
        const int rowbase = rr * 32 + w * 8;
        gload_lds16(base + 1024 + (size_t)(rowbase + (l >> 3)) * 3072 + kswz,
                    &Ks[0][rowbase * 64]);
    }
    {
        const short* vp = base + 2048 + (size_t)k0v * 3072 + seg;
        KA.q[0] = *(const uint4*)vp;
        KA.q[1] = *(const uint4*)(vp + 8);
        KB.q[0] = *(const uint4*)(vp + 3072);
        KB.q[1] = *(const uint4*)(vp + 3080);
#pragma unroll
        for (int dd = 0; dd < 16; ++dd) {
            const unsigned int w0 = KA.u[dd >> 1];
            const unsigned int w1 = KB.u[dd >> 1];
            const unsigned int pk = (dd & 1) ? ((w0 >> 16) | (w1 & 0xffff0000u))
                                             : ((w0 & 0xffffu) | (w1 << 16));
            *(unsigned int*)&Vt[0][(seg + dd) * 128 + ((vg ^ dd) << 3) + vpo] = pk;
        }
    }
    __syncthreads();

#pragma unroll 1
    for (int it = 0; it < nkt; ++it) {
        const int j0  = it * 128;
        const int buf = it & 1;
        const int nb  = buf ^ 1;

        // --- issue next-tile prefetch before compute (latency hides) ---
        if (it + 1 < nkt) {
            const int j1 = j0 + 128;
#pragma unroll
            for (int rr = 0; rr < 4; ++rr) {
                const int rowbase = rr * 32 + w * 8;
                gload_lds16(base + 1024 + (size_t)(j1 + rowbase + (l >> 3)) * 3072 + kswz,
                            &Ks[nb][rowbase * 64]);
            }
            const short* vp = base + 2048 + (size_t)(j1 + k0v) * 3072 + seg;
            KA.q[0] = *(const uint4*)vp;
            KA.q[1] = *(const uint4*)(vp + 8);
            KB.q[0] = *(const uint4*)(vp + 3072);
            KB.q[1] = *(const uint4*)(vp + 3080);
        }

        // --- S^T = K Q^T: s4[kb] covers keys kb*32.., col = q ---
        f32x16 s4[4];
        __builtin_amdgcn_s_setprio(1);
#pragma unroll
        for (int kb = 0; kb < 4; ++kb) {
            const short* krp = &Ks[buf][(kb * 32 + c31) * 64];
            const int sw = c31 & 7;
            f32x16 a;
#pragma unroll
            for (int r = 0; r < 16; ++r) a[r] = 0.f;
#pragma unroll
            for (int ds = 0; ds < 4; ++ds) {
                const bf16x8 kf = *(const bf16x8*)&krp[((ds * 2 + hi) ^ sw) << 3];
                a = __builtin_amdgcn_mfma_f32_32x32x16_bf16(kf, qf[ds], a, 0, 0, 0);
            }
            s4[kb] = a;
        }
        __builtin_amdgcn_s_setprio(0);

        // --- causal mask (last tile only) ---
        if (it == nkt - 1) {
#pragma unroll
            for (int kb = 0; kb < 4; ++kb)
#pragma unroll
                for (int r = 0; r < 16; ++r) {
                    const int key = j0 + kb * 32 + (r & 3) + 8 * (r >> 2) + 4 * hi;
                    if (key > q_abs) s4[kb][r] = -1e30f;
                }
        }

        // --- online softmax: in-thread tree + ONE shfl hop ---
        float tm[4];
#pragma unroll
        for (int kb = 0; kb < 4; ++kb) {
            float a0 = fmaxf(fmaxf(s4[kb][0], s4[kb][1]), fmaxf(s4[kb][2], s4[kb][3]));
            float a1 = fmaxf(fmaxf(s4[kb][4], s4[kb][5]), fmaxf(s4[kb][6], s4[kb][7]));
            float a2 = fmaxf(fmaxf(s4[kb][8], s4[kb][9]), fmaxf(s4[kb][10], s4[kb][11]));
            float a3 = fmaxf(fmaxf(s4[kb][12], s4[kb][13]), fmaxf(s4[kb][14], s4[kb][15]));
            tm[kb] = fmaxf(fmaxf(a0, a1), fmaxf(a2, a3));
        }
        float mx = fmaxf(fmaxf(tm[0], tm[1]), fmaxf(tm[2], tm[3]));
        mx = fmaxf(mx, __shfl_xor(mx, 32));

        const bool grow = __any(mx > m_run);
        float corr = 1.f;
        if (grow) {
            const float mn = fmaxf(m_run, mx);
            corr = EXP2((m_run - mn) * SC);
            m_run = mn;
        }
        const float nmc = -m_run * SC;
#pragma unroll
        for (int kb = 0; kb < 4; ++kb)
#pragma unroll
            for (int r = 0; r < 16; ++r)
                s4[kb][r] = EXP2(fmaf(s4[kb][r], SC, nmc));

        float ts[4];
#pragma unroll
        for (int kb = 0; kb < 4; ++kb) {
            float a0 = (s4[kb][0] + s4[kb][1]) + (s4[kb][2] + s4[kb][3]);
            float a1 = (s4[kb][4] + s4[kb][5]) + (s4[kb][6] + s4[kb][7]);
            float a2 = (s4[kb][8] + s4[kb][9]) + (s4[kb][10] + s4[kb][11]);
            float a3 = (s4[kb][12] + s4[kb][13]) + (s4[kb][14] + s4[kb][15]);
            ts[kb] = (a0 + a1) + (a2 + a3);
        }
        const float ps = (ts[0] + ts[1]) + (ts[2] + ts[3]);
        lacc = grow ? (lacc * corr + ps) : (lacc + ps);

        if (grow) {
#pragma unroll
            for (int dt = 0; dt < 2; ++dt)
#pragma unroll
                for (int r = 0; r < 16; ++r) acc_o[dt][r] *= corr;
        }

        // --- O^T += V^T P^T: pf straight from regs; vf one b128 read ---
        __builtin_amdgcn_s_setprio(1);
#pragma unroll
        for (int kb = 0; kb < 4; ++kb) {
#pragma unroll
            for (int hh = 0; hh < 2; ++hh) {
                union { unsigned int u[4]; bf16x8 v; } up;
#pragma unroll
                for (int p = 0; p < 4; ++p)
                    up.u[p] = (unsigned int)(unsigned short)f2bf(s4[kb][hh * 8 + 2 * p])
                            | ((unsigned int)(unsigned short)f2bf(s4[kb][hh * 8 + 2 * p + 1]) << 16);
                const int g = kb * 4 + hh * 2 + hi;
#pragma unroll
                for (int dt = 0; dt < 2; ++dt) {
                    const bf16x8 vf = *(const bf16x8*)
                        &Vt[buf][(dt * 32 + c31) * 128 + ((g ^ dmask) << 3)];
                    acc_o[dt] = __builtin_amdgcn_mfma_f32_32x32x16_bf16(vf, up.v, acc_o[dt], 0, 0, 0);
                }
            }
        }
        __builtin_amdgcn_s_setprio(0);

        // --- write prefetched V into spare buffer (after its readers) ---
        if (it + 1 < nkt) {
#pragma unroll
            for (int dd = 0; dd < 16; ++dd) {
                const unsigned int w0 = KA.u[dd >> 1];
                const unsigned int w1 = KB.u[dd >> 1];
                const unsigned int pk = (dd & 1) ? ((w0 >> 16) | (w1 & 0xffff0000u))
                                                 : ((w0 & 0xffffu) | (w1 << 16));
                *(unsigned int*)&Vt[nb][(seg + dd) * 128 + ((vg ^ dd) << 3) + vpo] = pk;
            }
        }

        __syncthreads();   // drains K gloads + V writes, frees old buffers
    }

    // --- epilogue: O[q][d] = O^T[d][q]/l ---
    const float ls  = lacc + __shfl_xor(lacc, 32);
    const float inv = 1.f / ls;
    short* op = att + ((size_t)(b * T + q_abs)) * 1024 + h * 64;
#pragma unroll
    for (int dt = 0; dt < 2; ++dt)
#pragma unroll
        for (int rg = 0; rg < 4; ++rg) {
            const int d0 = dt * 32 + 8 * rg + 4 * hi;
            short4 pk;
            pk.x = f2bf(acc_o[dt][rg * 4 + 0] * inv);
            pk.y = f2bf(acc_o[dt][rg * 4 + 1] * inv);
            pk.z = f2bf(acc_o[dt][rg * 4 + 2] * inv);
            pk.w = f2bf(acc_o[dt][rg * 4 + 3] * inv);
            *(short4*)(op + d0) = pk;
        }
}

// ---------------------------------------------------------------------------
extern "C" void kernel_launch(void* const* d_in, const int* in_sizes, int n_in,
                              void* d_out, int out_size, void* d_ws, size_t ws_size,
                              hipStream_t stream)
{
    const float* x      = (const float*)d_in[0];   // [B,T,C]
    const float* w_qkv  = (const float*)d_in[1];   // [C,3C]
    const float* b_qkv  = (const float*)d_in[2];   // [3C]
    const float* w_proj = (const float*)d_in[3];   // [C,C]
    const float* b_proj = (const float*)d_in[4];   // [C]
    float* out = (float*)d_out;                    // [B,T,C] fp32

    short* xb     = (short*)d_ws;                        //  8 MB
    short* wqkvt  = xb     + (size_t)M * C;              //  6 MB  [3072][1024]
    short* wprojt = wqkvt  + (size_t)NQKV * C;           //  2 MB  [1024][1024]
    short* qkvb   = wprojt + (size_t)C * C;              // 24 MB  [4096][3072]
    short* attb   = qkvb   + (size_t)M * NQKV;           //  8 MB  [4096][1024]

    prep_all<<<8192, 256, 0, stream>>>(x, xb, w_qkv, wqkvt, w_proj, wprojt);
    gemm_mfma<<<dim3(NQKV / 128, M / 128), 256, 0, stream>>>(xb, wqkvt, b_qkv, qkvb, NQKV, C);
    attn_mfma<<<512, 256, 0, stream>>>(qkvb, attb);
    gemm_mfma_proj<<<dim3(C / 128, M / 64), 256, 0, stream>>>(attb, wprojt, b_proj, out, C, C);
}

// Round 5
// 186.926 us; speedup vs baseline: 1.0529x; 1.0529x over previous
//
#include <hip/hip_runtime.h>
#include <hip/hip_bf16.h>
#include <math.h>

// Problem constants (reference: B=2, T=2048, D_MODEL=1024, N_HEAD=16, D_HEAD=64)
constexpr int Bb   = 2;
constexpr int T    = 2048;
constexpr int C    = 1024;
constexpr int H    = 16;
constexpr int M    = Bb * T;   // 4096 rows
constexpr int NQKV = 3 * C;    // 3072

typedef __attribute__((ext_vector_type(8))) short bf16x8;
typedef __attribute__((ext_vector_type(4))) float f32x4;

__device__ inline short f2bf(float f) {
    __hip_bfloat16 h = __float2bfloat16(f);
    return *reinterpret_cast<short*>(&h);
}

#if __has_builtin(__builtin_amdgcn_exp2f)
#define EXP2(x) __builtin_amdgcn_exp2f(x)
#else
#define EXP2(x) exp2f(x)
#endif

#define GLOBAL_AS __attribute__((address_space(1)))
#define LDS_AS    __attribute__((address_space(3)))

__device__ __forceinline__ void gload_lds16(const short* g, short* s) {
    __builtin_amdgcn_global_load_lds((const GLOBAL_AS void*)g, (LDS_AS void*)s, 16, 0, 0);
}

// ---------------------------------------------------------------------------
// Fused prep: x->bf16 (blocks 0..4095), w_qkv transpose (4096..7167),
// w_proj transpose (7168..8191). + zeroes the attn work queue counter.
// ---------------------------------------------------------------------------
__global__ __launch_bounds__(256)
void prep_all(const float* __restrict__ x, short* __restrict__ xb,
              const float* __restrict__ w_qkv, short* __restrict__ wqkvt,
              const float* __restrict__ w_proj, short* __restrict__ wprojt,
              int* __restrict__ qcnt)
{
    __shared__ float tile[32][33];
    const int blk = blockIdx.x;
    const int tid = threadIdx.x;

    if (blk == 0 && tid == 0) *qcnt = 0;   // reset attn steal queue each iter

    if (blk < 4096) {                       // cvt x
        const int i = blk * 1024 + tid * 4;
        const float4 v = *(const float4*)(x + i);
        short4 s;
        s.x = f2bf(v.x); s.y = f2bf(v.y); s.z = f2bf(v.z); s.w = f2bf(v.w);
        *(short4*)(xb + i) = s;
        return;
    }

    const bool isqkv = (blk < 7168);
    const int bidx = isqkv ? (blk - 4096) : (blk - 7168);
    const int nblk = isqkv ? 96 : 32;       // N/32
    const int N    = isqkv ? NQKV : C;
    const float* W = isqkv ? w_qkv : w_proj;
    short* Wt      = isqkv ? wqkvt : wprojt;

    const int n0 = (bidx % nblk) * 32, k0 = (bidx / nblk) * 32;
    const int tx = tid & 31, ty = tid >> 5;   // 32 x 8
#pragma unroll
    for (int i = 0; i < 32; i += 8)
        tile[ty + i][tx] = W[(size_t)(k0 + ty + i) * N + n0 + tx];
    __syncthreads();
#pragma unroll
    for (int i = 0; i < 32; i += 8)
        Wt[(size_t)(n0 + ty + i) * C + k0 + tx] = f2bf(tile[tx][ty + i]);
}

// ---------------------------------------------------------------------------
// QKV GEMM: 128x128 tile, BK=32, 2-phase prefetch double-buffer + XCD swizzle.
// Unchanged from R1.
// ---------------------------------------------------------------------------
__global__ __launch_bounds__(256)
void gemm_mfma(const short* __restrict__ A, const short* __restrict__ Bt,
               const float* __restrict__ bias, short* __restrict__ outp,
               int Ndim, int Kdim)
{
    __shared__ __align__(16) short As[2 * 128 * 32];   // 16 KB (double-buffered)
    __shared__ __align__(16) short Bs[2 * 128 * 32];   // 16 KB

    const int tid = threadIdx.x;
    const int w   = tid >> 6;
    const int l   = tid & 63;
    const int lk  = l & 15;
    const int lq  = l >> 4;

    const int gx  = gridDim.x;
    const int nwg = gx * gridDim.y;          // 768, divisible by 8
    const int cpx = nwg >> 3;
    const int bid = blockIdx.y * gx + blockIdx.x;
    const int swz = (bid & 7) * cpx + (bid >> 3);
    const int m0  = (swz / gx) * 128;
    const int n0  = (swz % gx) * 128;

    const int mw  = (w >> 1) * 64, nw = (w & 1) * 64;

    const int srow = w * 16 + (l >> 2);
    const int scol = (l & 3) * 8;

    const short* agp0 = A  + (size_t)(m0 + srow)      * Kdim + scol;
    const short* agp1 = A  + (size_t)(m0 + 64 + srow) * Kdim + scol;
    const short* bgp0 = Bt + (size_t)(n0 + srow)      * Kdim + scol;
    const short* bgp1 = Bt + (size_t)(n0 + 64 + srow) * Kdim + scol;

    short* ad0 = &As[w * 512];
    short* ad1 = &As[2048 + w * 512];
    short* bd0 = &Bs[w * 512];
    short* bd1 = &Bs[2048 + w * 512];

    f32x4 acc[4][4];
#pragma unroll
    for (int i = 0; i < 4; ++i)
#pragma unroll
        for (int j = 0; j < 4; ++j) acc[i][j] = (f32x4){0.f, 0.f, 0.f, 0.f};

    gload_lds16(agp0, ad0);
    gload_lds16(agp1, ad1);
    gload_lds16(bgp0, bd0);
    gload_lds16(bgp1, bd1);
    __syncthreads();

    int cur = 0;
    for (int k0 = 0; k0 < Kdim; k0 += 32) {
        const int coff = cur ? 4096 : 0;

        bf16x8 af[4], bfr[4];
#pragma unroll
        for (int mt = 0; mt < 4; ++mt)
            af[mt] = *(const bf16x8*)&As[coff + (mw + mt * 16 + lk) * 32 + lq * 8];
#pragma unroll
        for (int nt = 0; nt < 4; ++nt)
            bfr[nt] = *(const bf16x8*)&Bs[coff + (nw + nt * 16 + lk) * 32 + lq * 8];

        if (k0 + 32 < Kdim) {
            const int noff = cur ? 0 : 4096;
            gload_lds16(agp0 + k0 + 32, ad0 + noff);
            gload_lds16(agp1 + k0 + 32, ad1 + noff);
            gload_lds16(bgp0 + k0 + 32, bd0 + noff);
            gload_lds16(bgp1 + k0 + 32, bd1 + noff);
        }

#pragma unroll
        for (int mt = 0; mt < 4; ++mt)
#pragma unroll
            for (int nt = 0; nt < 4; ++nt)
                acc[mt][nt] = __builtin_amdgcn_mfma_f32_16x16x32_bf16(bfr[nt], af[mt], acc[mt][nt], 0, 0, 0);

        __syncthreads();
        cur ^= 1;
    }

    float4 bv[4];
#pragma unroll
    for (int nt = 0; nt < 4; ++nt)
        bv[nt] = *(const float4*)(bias + n0 + nw + nt * 16 + lq * 4);
#pragma unroll
    for (int mt = 0; mt < 4; ++mt) {
        short* rowp = outp + (size_t)(m0 + mw + mt * 16 + lk) * Ndim + n0 + nw + lq * 4;
#pragma unroll
        for (int nt = 0; nt < 4; ++nt) {
            short4 pk;
            pk.x = f2bf(acc[mt][nt][0] + bv[nt].x);
            pk.y = f2bf(acc[mt][nt][1] + bv[nt].y);
            pk.z = f2bf(acc[mt][nt][2] + bv[nt].z);
            pk.w = f2bf(acc[mt][nt][3] + bv[nt].w);
            *(short4*)(rowp + nt * 16) = pk;
        }
    }
}

// ---------------------------------------------------------------------------
// Proj GEMM: 64x128 tile, BK=32, 2-phase prefetch + XCD swizzle. Unchanged.
// ---------------------------------------------------------------------------
__global__ __launch_bounds__(256)
void gemm_mfma_proj(const short* __restrict__ A, const short* __restrict__ Bt,
                    const float* __restrict__ bias, float* __restrict__ outp,
                    int Ndim, int Kdim)
{
    __shared__ __align__(16) short As[2 * 64 * 32];    //  8 KB
    __shared__ __align__(16) short Bs[2 * 128 * 32];   // 16 KB

    const int tid = threadIdx.x;
    const int w   = tid >> 6;
    const int l   = tid & 63;
    const int lk  = l & 15;
    const int lq  = l >> 4;

    const int gx  = gridDim.x;
    const int nwg = gx * gridDim.y;          // 512, divisible by 8
    const int cpx = nwg >> 3;
    const int bid = blockIdx.y * gx + blockIdx.x;
    const int swz = (bid & 7) * cpx + (bid >> 3);
    const int m0  = (swz / gx) * 64;
    const int n0  = (swz % gx) * 128;

    const int mw  = (w & 1) * 32, nw = (w >> 1) * 64;

    const int srow = w * 16 + (l >> 2);
    const int scol = (l & 3) * 8;

    const short* agp  = A  + (size_t)(m0 + srow)      * Kdim + scol;
    const short* bgp0 = Bt + (size_t)(n0 + srow)      * Kdim + scol;
    const short* bgp1 = Bt + (size_t)(n0 + 64 + srow) * Kdim + scol;

    short* ad  = &As[w * 512];
    short* bd0 = &Bs[w * 512];
    short* bd1 = &Bs[2048 + w * 512];

    f32x4 acc[2][4];
#pragma unroll
    for (int i = 0; i < 2; ++i)
#pragma unroll
        for (int j = 0; j < 4; ++j) acc[i][j] = (f32x4){0.f, 0.f, 0.f, 0.f};

    gload_lds16(agp,  ad);
    gload_lds16(bgp0, bd0);
    gload_lds16(bgp1, bd1);
    __syncthreads();

    int cur = 0;
    for (int k0 = 0; k0 < Kdim; k0 += 32) {
        const int coffA = cur ? 2048 : 0;
        const int coffB = cur ? 4096 : 0;

        bf16x8 af[2], bfr[4];
#pragma unroll
        for (int mt = 0; mt < 2; ++mt)
            af[mt] = *(const bf16x8*)&As[coffA + (mw + mt * 16 + lk) * 32 + lq * 8];
#pragma unroll
        for (int nt = 0; nt < 4; ++nt)
            bfr[nt] = *(const bf16x8*)&Bs[coffB + (nw + nt * 16 + lk) * 32 + lq * 8];

        if (k0 + 32 < Kdim) {
            const int noffA = cur ? 0 : 2048;
            const int noffB = cur ? 0 : 4096;
            gload_lds16(agp  + k0 + 32, ad  + noffA);
            gload_lds16(bgp0 + k0 + 32, bd0 + noffB);
            gload_lds16(bgp1 + k0 + 32, bd1 + noffB);
        }

#pragma unroll
        for (int mt = 0; mt < 2; ++mt)
#pragma unroll
            for (int nt = 0; nt < 4; ++nt)
                acc[mt][nt] = __builtin_amdgcn_mfma_f32_16x16x32_bf16(bfr[nt], af[mt], acc[mt][nt], 0, 0, 0);

        __syncthreads();
        cur ^= 1;
    }

    float4 bv[4];
#pragma unroll
    for (int nt = 0; nt < 4; ++nt)
        bv[nt] = *(const float4*)(bias + n0 + nw + nt * 16 + lq * 4);
#pragma unroll
    for (int mt = 0; mt < 2; ++mt) {
        float* rowp = outp + (size_t)(m0 + mw + mt * 16 + lk) * Ndim + n0 + nw + lq * 4;
#pragma unroll
        for (int nt = 0; nt < 4; ++nt) {
            float4 v;
            v.x = acc[mt][nt][0] + bv[nt].x;
            v.y = acc[mt][nt][1] + bv[nt].y;
            v.z = acc[mt][nt][2] + bv[nt].z;
            v.w = acc[mt][nt][3] + bv[nt].w;
            *(float4*)(rowp + nt * 16) = v;
        }
    }
}

// ---------------------------------------------------------------------------
// MFMA flash attention v12: WORK-STEALING equal balance, 3 blocks/CU.
//  - 1024 work units = (bh, 64-row q-tile), sorted LONGEST-FIRST
//    (qt = 31 - (u>>5)). 768 blocks x 4 waves; block starts with
//    unit = blockIdx then steals via global atomic counter. Balance holds
//    regardless of dispatch order / block->CU placement.
//  - KVBLK=64, K+V double-buffered, single barrier per tile, K prefetch via
//    gload_lds + V via regs issued before compute (v9's proven pipeline).
//  - LDS 42.6 KB (LDV=104 pad) -> exactly 3 blocks/CU = 12 waves/CU.
//  - 16x16 S^T formulation, XOR-swizzled Ks, slot-permuted Vt (v10-verified
//    map), register-direct PV, exact defer-max, setprio on MFMA clusters.
// ---------------------------------------------------------------------------
constexpr int LDV = 104;            // Vt padded leading dim (also LDS pad ->3/CU)
constexpr float SC = 0.18033688f;   // 0.125 * log2(e)
constexpr int NUNITS = 1024;
constexpr int NBLK   = 768;

__global__ __launch_bounds__(256, 3)
void attn_mfma(const short* __restrict__ qkv, short* __restrict__ att,
               int* __restrict__ qcnt)
{
    __shared__ __align__(16) short Ks[2][64 * 64];    // 2x8 KB, granule^row&7
    __shared__ __align__(16) short Vt[2][64 * LDV];   // 2x13.3 KB, slot-permuted
    __shared__ int s_unit;

    const int tid = threadIdx.x;
    const int w   = tid >> 6;            // 0..3
    const int l   = tid & 63;
    const int lk  = l & 15;
    const int lq  = l >> 4;

    // K staging: lane l -> granule (l&7) of row (l>>3) in an 8-row group;
    // source dim-block XOR'd so reads de-conflict.
    const int kswz = 8 * ((l & 7) ^ (l >> 3));
    const int swz  = lk & 7;

    // V staging: thread owns keys {2k2, 2k2+1}, dims vd0..vd0+7
    const int k2  = tid & 31;            // 32 key-pairs = 64 keys
    const int vd0 = (tid >> 5) * 8;      // 8 dim-groups
    const int kk  = 2 * k2;
    const int w5  = kk & 31;
    const int vcol = (kk >> 5) * 32 + ((w5 >> 2) & 3) * 8
                   + ((w5 >> 4) & 1) * 4 + (w5 & 3);   // even; key+1 -> vcol+1

    uint4 va, vb;                        // in-flight V registers

    int unit = blockIdx.x;
    while (true) {
        const int qt = 31 - (unit >> 5); // longest-first
        const int bh = unit & 31;
        const int b  = bh >> 4;
        const int h  = bh & 15;
        const int qbase = qt * 64;
        const int nkt   = qt + 1;

        const short* base = qkv + (size_t)b * T * 3072 + h * 64;

        const int q_abs = qbase + w * 16 + lk;
        const short* qp = base + (size_t)q_abs * 3072 + lq * 8;
        const bf16x8 qf0 = *(const bf16x8*)qp;
        const bf16x8 qf1 = *(const bf16x8*)(qp + 32);

        f32x4 acc_o[4];
#pragma unroll
        for (int dt = 0; dt < 4; ++dt) acc_o[dt] = (f32x4){0.f, 0.f, 0.f, 0.f};
        float m_run = -INFINITY;
        float l_run = 0.f;

        // ---- prologue: stage tile 0 into buffer 0 ----
#pragma unroll
        for (int rr = 0; rr < 2; ++rr) {
            const int rowbase = rr * 32 + w * 8;
            gload_lds16(base + 1024 + (size_t)(rowbase + (l >> 3)) * 3072 + kswz,
                        &Ks[0][rowbase * 64]);
        }
        {
            const short* vp = base + 2048 + (size_t)kk * 3072 + vd0;
            va = *(const uint4*)vp;
            vb = *(const uint4*)(vp + 3072);
            const unsigned int Aa[4] = {va.x, va.y, va.z, va.w};
            const unsigned int Bv[4] = {vb.x, vb.y, vb.z, vb.w};
#pragma unroll
            for (int p = 0; p < 4; ++p) {
                const unsigned int ue = (Aa[p] & 0xffffu) | (Bv[p] << 16);
                const unsigned int uo = (Aa[p] >> 16) | (Bv[p] & 0xffff0000u);
                *(unsigned int*)&Vt[0][(vd0 + 2 * p)     * LDV + vcol] = ue;
                *(unsigned int*)&Vt[0][(vd0 + 2 * p + 1) * LDV + vcol] = uo;
            }
        }
        __syncthreads();

#pragma unroll 1
        for (int it = 0; it < nkt; ++it) {
            const int j0  = it * 64;
            const int buf = it & 1;
            const int nb  = buf ^ 1;

            // --- issue next-tile prefetch before compute (latency hides) ---
            if (it + 1 < nkt) {
                const int j1 = j0 + 64;
#pragma unroll
                for (int rr = 0; rr < 2; ++rr) {
                    const int rowbase = rr * 32 + w * 8;
                    gload_lds16(base + 1024 + (size_t)(j1 + rowbase + (l >> 3)) * 3072 + kswz,
                                &Ks[nb][rowbase * 64]);
                }
                const short* vp = base + 2048 + (size_t)(j1 + kk) * 3072 + vd0;
                va = *(const uint4*)vp;
                vb = *(const uint4*)(vp + 3072);
            }

            // --- S^T = K Q^T: s4[kt][r] = S[key=j0+kt*16+lq*4+r][q=lk] ---
            f32x4 s4[4];
            __builtin_amdgcn_s_setprio(1);
#pragma unroll
            for (int kt = 0; kt < 4; ++kt) {
                const int row = kt * 16 + lk;
                const bf16x8 kf0 = *(const bf16x8*)&Ks[buf][row * 64 + 8 * (lq ^ swz)];
                const bf16x8 kf1 = *(const bf16x8*)&Ks[buf][row * 64 + 8 * ((lq + 4) ^ swz)];
                f32x4 a = (f32x4){0.f, 0.f, 0.f, 0.f};
                a = __builtin_amdgcn_mfma_f32_16x16x32_bf16(kf0, qf0, a, 0, 0, 0);
                a = __builtin_amdgcn_mfma_f32_16x16x32_bf16(kf1, qf1, a, 0, 0, 0);
                s4[kt] = a;
            }
            __builtin_amdgcn_s_setprio(0);

            // --- causal mask (last tile only; exactly the diagonal tile) ---
            if (it == nkt - 1) {
#pragma unroll
                for (int kt = 0; kt < 4; ++kt)
#pragma unroll
                    for (int r2 = 0; r2 < 4; ++r2)
                        if (j0 + kt * 16 + lq * 4 + r2 > q_abs) s4[kt][r2] = -1e30f;
            }

            // --- online softmax: tree max + 2 shfl hops ---
            float tm[4];
#pragma unroll
            for (int kt = 0; kt < 4; ++kt)
                tm[kt] = fmaxf(fmaxf(s4[kt][0], s4[kt][1]), fmaxf(s4[kt][2], s4[kt][3]));
            float mx = fmaxf(fmaxf(tm[0], tm[1]), fmaxf(tm[2], tm[3]));
            mx = fmaxf(mx, __shfl_xor(mx, 16));
            mx = fmaxf(mx, __shfl_xor(mx, 32));

            const bool grow = __any(mx > m_run);
            float corr = 1.f;
            if (grow) {
                const float mn = fmaxf(m_run, mx);
                corr = EXP2((m_run - mn) * SC);
                m_run = mn;
            }
            const float nmc = -m_run * SC;
#pragma unroll
            for (int kt = 0; kt < 4; ++kt)
#pragma unroll
                for (int r2 = 0; r2 < 4; ++r2)
                    s4[kt][r2] = EXP2(fmaf(s4[kt][r2], SC, nmc));

            float ts[4];
#pragma unroll
            for (int kt = 0; kt < 4; ++kt)
                ts[kt] = (s4[kt][0] + s4[kt][1]) + (s4[kt][2] + s4[kt][3]);
            float ps = (ts[0] + ts[1]) + (ts[2] + ts[3]);
            ps += __shfl_xor(ps, 16);
            ps += __shfl_xor(ps, 32);
            l_run = grow ? (l_run * corr + ps) : (l_run + ps);

            // --- pack P rows to dwords ---
            unsigned int d0[4], d1[4];
#pragma unroll
            for (int kt = 0; kt < 4; ++kt) {
                d0[kt] = (unsigned int)(unsigned short)f2bf(s4[kt][0])
                       | ((unsigned int)(unsigned short)f2bf(s4[kt][1]) << 16);
                d1[kt] = (unsigned int)(unsigned short)f2bf(s4[kt][2])
                       | ((unsigned int)(unsigned short)f2bf(s4[kt][3]) << 16);
            }

            if (grow) {
#pragma unroll
                for (int dt = 0; dt < 4; ++dt)
#pragma unroll
                    for (int r2 = 0; r2 < 4; ++r2) acc_o[dt][r2] *= corr;
            }

            // --- O^T += V^T P^T: pf straight from regs; vf one b128 read ---
            __builtin_amdgcn_s_setprio(1);
#pragma unroll
            for (int kc = 0; kc < 2; ++kc) {
                union { unsigned int u[4]; bf16x8 v; } up;
                up.u[0] = d0[kc * 2];
                up.u[1] = d1[kc * 2];
                up.u[2] = d0[kc * 2 + 1];
                up.u[3] = d1[kc * 2 + 1];
                const bf16x8 pf = up.v;
#pragma unroll
                for (int dt = 0; dt < 4; ++dt) {
                    const bf16x8 vf = *(const bf16x8*)&Vt[buf][(dt * 16 + lk) * LDV + kc * 32 + lq * 8];
                    acc_o[dt] = __builtin_amdgcn_mfma_f32_16x16x32_bf16(vf, pf, acc_o[dt], 0, 0, 0);
                }
            }
            __builtin_amdgcn_s_setprio(0);

            // --- write prefetched V into spare buffer (after its readers) ---
            if (it + 1 < nkt) {
                const unsigned int Aa[4] = {va.x, va.y, va.z, va.w};
                const unsigned int Bv[4] = {vb.x, vb.y, vb.z, vb.w};
#pragma unroll
                for (int p = 0; p < 4; ++p) {
                    const unsigned int ue = (Aa[p] & 0xffffu) | (Bv[p] << 16);
                    const unsigned int uo = (Aa[p] >> 16) | (Bv[p] & 0xffff0000u);
                    *(unsigned int*)&Vt[nb][(vd0 + 2 * p)     * LDV + vcol] = ue;
                    *(unsigned int*)&Vt[nb][(vd0 + 2 * p + 1) * LDV + vcol] = uo;
                }
            }

            __syncthreads();   // drains K gloads + V writes, frees old buffers
        }

        // --- epilogue: O[q][d] = O^T[d][q]/l ---
        const float inv = 1.f / l_run;
        short* op = att + ((size_t)(b * T + q_abs)) * 1024 + h * 64;
#pragma unroll
        for (int dt = 0; dt < 4; ++dt) {
            short4 pk;
            pk.x = f2bf(acc_o[dt][0] * inv);
            pk.y = f2bf(acc_o[dt][1] * inv);
            pk.z = f2bf(acc_o[dt][2] * inv);
            pk.w = f2bf(acc_o[dt][3] * inv);
            *(short4*)(op + dt * 16 + lq * 4) = pk;
        }

        // --- steal next unit (device-scope atomic; uniform per block) ---
        if (tid == 0) s_unit = NBLK + atomicAdd(qcnt, 1);
        __syncthreads();            // orders s_unit AND protects LDS restage
        unit = s_unit;
        if (unit >= NUNITS) break;
    }
}

// ---------------------------------------------------------------------------
extern "C" void kernel_launch(void* const* d_in, const int* in_sizes, int n_in,
                              void* d_out, int out_size, void* d_ws, size_t ws_size,
                              hipStream_t stream)
{
    const float* x      = (const float*)d_in[0];   // [B,T,C]
    const float* w_qkv  = (const float*)d_in[1];   // [C,3C]
    const float* b_qkv  = (const float*)d_in[2];   // [3C]
    const float* w_proj = (const float*)d_in[3];   // [C,C]
    const float* b_proj = (const float*)d_in[4];   // [C]
    float* out = (float*)d_out;                    // [B,T,C] fp32

    short* xb     = (short*)d_ws;                        //  8 MB
    short* wqkvt  = xb     + (size_t)M * C;              //  6 MB  [3072][1024]
    short* wprojt = wqkvt  + (size_t)NQKV * C;           //  2 MB  [1024][1024]
    short* qkvb   = wprojt + (size_t)C * C;              // 24 MB  [4096][3072]
    short* attb   = qkvb   + (size_t)M * NQKV;           //  8 MB  [4096][1024]
    int*   qcnt   = (int*)(attb + (size_t)M * C);        //  4 B   steal counter

    prep_all<<<8192, 256, 0, stream>>>(x, xb, w_qkv, wqkvt, w_proj, wprojt, qcnt);
    gemm_mfma<<<dim3(NQKV / 128, M / 128), 256, 0, stream>>>(xb, wqkvt, b_qkv, qkvb, NQKV, C);
    attn_mfma<<<NBLK, 256, 0, stream>>>(qkvb, attb, qcnt);
    gemm_mfma_proj<<<dim3(C / 128, M / 64), 256, 0, stream>>>(attb, wprojt, b_proj, out, C, C);
}

// Round 6
// 174.084 us; speedup vs baseline: 1.1306x; 1.0738x over previous
//
#include <hip/hip_runtime.h>
#include <hip/hip_bf16.h>
#include <math.h>

// Problem constants (reference: B=2, T=2048, D_MODEL=1024, N_HEAD=16, D_HEAD=64)
constexpr int Bb   = 2;
constexpr int T    = 2048;
constexpr int C    = 1024;
constexpr int H    = 16;
constexpr int M    = Bb * T;   // 4096 rows
constexpr int NQKV = 3 * C;    // 3072

typedef __attribute__((ext_vector_type(8))) short bf16x8;
typedef __attribute__((ext_vector_type(4))) float f32x4;

__device__ inline short f2bf(float f) {
    __hip_bfloat16 h = __float2bfloat16(f);
    return *reinterpret_cast<short*>(&h);
}

#if __has_builtin(__builtin_amdgcn_exp2f)
#define EXP2(x) __builtin_amdgcn_exp2f(x)
#else
#define EXP2(x) exp2f(x)
#endif

#define GLOBAL_AS __attribute__((address_space(1)))
#define LDS_AS    __attribute__((address_space(3)))

__device__ __forceinline__ void gload_lds16(const short* g, short* s) {
    __builtin_amdgcn_global_load_lds((const GLOBAL_AS void*)g, (LDS_AS void*)s, 16, 0, 0);
}

// ---------------------------------------------------------------------------
// Fused prep: x->bf16 (blocks 0..4095), w_qkv transpose (4096..7167),
// w_proj transpose (7168..8191). Unchanged (R2-proven).
// ---------------------------------------------------------------------------
__global__ __launch_bounds__(256)
void prep_all(const float* __restrict__ x, short* __restrict__ xb,
              const float* __restrict__ w_qkv, short* __restrict__ wqkvt,
              const float* __restrict__ w_proj, short* __restrict__ wprojt)
{
    __shared__ float tile[32][33];
    const int blk = blockIdx.x;
    const int tid = threadIdx.x;

    if (blk < 4096) {                       // cvt x
        const int i = blk * 1024 + tid * 4;
        const float4 v = *(const float4*)(x + i);
        short4 s;
        s.x = f2bf(v.x); s.y = f2bf(v.y); s.z = f2bf(v.z); s.w = f2bf(v.w);
        *(short4*)(xb + i) = s;
        return;
    }

    const bool isqkv = (blk < 7168);
    const int bidx = isqkv ? (blk - 4096) : (blk - 7168);
    const int nblk = isqkv ? 96 : 32;       // N/32
    const int N    = isqkv ? NQKV : C;
    const float* W = isqkv ? w_qkv : w_proj;
    short* Wt      = isqkv ? wqkvt : wprojt;

    const int n0 = (bidx % nblk) * 32, k0 = (bidx / nblk) * 32;
    const int tx = tid & 31, ty = tid >> 5;   // 32 x 8
#pragma unroll
    for (int i = 0; i < 32; i += 8)
        tile[ty + i][tx] = W[(size_t)(k0 + ty + i) * N + n0 + tx];
    __syncthreads();
#pragma unroll
    for (int i = 0; i < 32; i += 8)
        Wt[(size_t)(n0 + ty + i) * C + k0 + tx] = f2bf(tile[tx][ty + i]);
}

// ---------------------------------------------------------------------------
// QKV GEMM: 128x128 tile, BK=32, 2-phase prefetch double-buffer + XCD swizzle.
// Unchanged from R1 (proven).
// ---------------------------------------------------------------------------
__global__ __launch_bounds__(256)
void gemm_mfma(const short* __restrict__ A, const short* __restrict__ Bt,
               const float* __restrict__ bias, short* __restrict__ outp,
               int Ndim, int Kdim)
{
    __shared__ __align__(16) short As[2 * 128 * 32];   // 16 KB (double-buffered)
    __shared__ __align__(16) short Bs[2 * 128 * 32];   // 16 KB

    const int tid = threadIdx.x;
    const int w   = tid >> 6;
    const int l   = tid & 63;
    const int lk  = l & 15;
    const int lq  = l >> 4;

    const int gx  = gridDim.x;
    const int nwg = gx * gridDim.y;          // 768, divisible by 8
    const int cpx = nwg >> 3;
    const int bid = blockIdx.y * gx + blockIdx.x;
    const int swz = (bid & 7) * cpx + (bid >> 3);
    const int m0  = (swz / gx) * 128;
    const int n0  = (swz % gx) * 128;

    const int mw  = (w >> 1) * 64, nw = (w & 1) * 64;

    const int srow = w * 16 + (l >> 2);
    const int scol = (l & 3) * 8;

    const short* agp0 = A  + (size_t)(m0 + srow)      * Kdim + scol;
    const short* agp1 = A  + (size_t)(m0 + 64 + srow) * Kdim + scol;
    const short* bgp0 = Bt + (size_t)(n0 + srow)      * Kdim + scol;
    const short* bgp1 = Bt + (size_t)(n0 + 64 + srow) * Kdim + scol;

    short* ad0 = &As[w * 512];
    short* ad1 = &As[2048 + w * 512];
    short* bd0 = &Bs[w * 512];
    short* bd1 = &Bs[2048 + w * 512];

    f32x4 acc[4][4];
#pragma unroll
    for (int i = 0; i < 4; ++i)
#pragma unroll
        for (int j = 0; j < 4; ++j) acc[i][j] = (f32x4){0.f, 0.f, 0.f, 0.f};

    gload_lds16(agp0, ad0);
    gload_lds16(agp1, ad1);
    gload_lds16(bgp0, bd0);
    gload_lds16(bgp1, bd1);
    __syncthreads();

    int cur = 0;
    for (int k0 = 0; k0 < Kdim; k0 += 32) {
        const int coff = cur ? 4096 : 0;

        bf16x8 af[4], bfr[4];
#pragma unroll
        for (int mt = 0; mt < 4; ++mt)
            af[mt] = *(const bf16x8*)&As[coff + (mw + mt * 16 + lk) * 32 + lq * 8];
#pragma unroll
        for (int nt = 0; nt < 4; ++nt)
            bfr[nt] = *(const bf16x8*)&Bs[coff + (nw + nt * 16 + lk) * 32 + lq * 8];

        if (k0 + 32 < Kdim) {
            const int noff = cur ? 0 : 4096;
            gload_lds16(agp0 + k0 + 32, ad0 + noff);
            gload_lds16(agp1 + k0 + 32, ad1 + noff);
            gload_lds16(bgp0 + k0 + 32, bd0 + noff);
            gload_lds16(bgp1 + k0 + 32, bd1 + noff);
        }

#pragma unroll
        for (int mt = 0; mt < 4; ++mt)
#pragma unroll
            for (int nt = 0; nt < 4; ++nt)
                acc[mt][nt] = __builtin_amdgcn_mfma_f32_16x16x32_bf16(bfr[nt], af[mt], acc[mt][nt], 0, 0, 0);

        __syncthreads();
        cur ^= 1;
    }

    float4 bv[4];
#pragma unroll
    for (int nt = 0; nt < 4; ++nt)
        bv[nt] = *(const float4*)(bias + n0 + nw + nt * 16 + lq * 4);
#pragma unroll
    for (int mt = 0; mt < 4; ++mt) {
        short* rowp = outp + (size_t)(m0 + mw + mt * 16 + lk) * Ndim + n0 + nw + lq * 4;
#pragma unroll
        for (int nt = 0; nt < 4; ++nt) {
            short4 pk;
            pk.x = f2bf(acc[mt][nt][0] + bv[nt].x);
            pk.y = f2bf(acc[mt][nt][1] + bv[nt].y);
            pk.z = f2bf(acc[mt][nt][2] + bv[nt].z);
            pk.w = f2bf(acc[mt][nt][3] + bv[nt].w);
            *(short4*)(rowp + nt * 16) = pk;
        }
    }
}

// ---------------------------------------------------------------------------
// Proj GEMM: 64x128 tile, BK=32, 2-phase prefetch + XCD swizzle. Unchanged.
// ---------------------------------------------------------------------------
__global__ __launch_bounds__(256)
void gemm_mfma_proj(const short* __restrict__ A, const short* __restrict__ Bt,
                    const float* __restrict__ bias, float* __restrict__ outp,
                    int Ndim, int Kdim)
{
    __shared__ __align__(16) short As[2 * 64 * 32];    //  8 KB
    __shared__ __align__(16) short Bs[2 * 128 * 32];   // 16 KB

    const int tid = threadIdx.x;
    const int w   = tid >> 6;
    const int l   = tid & 63;
    const int lk  = l & 15;
    const int lq  = l >> 4;

    const int gx  = gridDim.x;
    const int nwg = gx * gridDim.y;          // 512, divisible by 8
    const int cpx = nwg >> 3;
    const int bid = blockIdx.y * gx + blockIdx.x;
    const int swz = (bid & 7) * cpx + (bid >> 3);
    const int m0  = (swz / gx) * 64;
    const int n0  = (swz % gx) * 128;

    const int mw  = (w & 1) * 32, nw = (w >> 1) * 64;

    const int srow = w * 16 + (l >> 2);
    const int scol = (l & 3) * 8;

    const short* agp  = A  + (size_t)(m0 + srow)      * Kdim + scol;
    const short* bgp0 = Bt + (size_t)(n0 + srow)      * Kdim + scol;
    const short* bgp1 = Bt + (size_t)(n0 + 64 + srow) * Kdim + scol;

    short* ad  = &As[w * 512];
    short* bd0 = &Bs[w * 512];
    short* bd1 = &Bs[2048 + w * 512];

    f32x4 acc[2][4];
#pragma unroll
    for (int i = 0; i < 2; ++i)
#pragma unroll
        for (int j = 0; j < 4; ++j) acc[i][j] = (f32x4){0.f, 0.f, 0.f, 0.f};

    gload_lds16(agp,  ad);
    gload_lds16(bgp0, bd0);
    gload_lds16(bgp1, bd1);
    __syncthreads();

    int cur = 0;
    for (int k0 = 0; k0 < Kdim; k0 += 32) {
        const int coffA = cur ? 2048 : 0;
        const int coffB = cur ? 4096 : 0;

        bf16x8 af[2], bfr[4];
#pragma unroll
        for (int mt = 0; mt < 2; ++mt)
            af[mt] = *(const bf16x8*)&As[coffA + (mw + mt * 16 + lk) * 32 + lq * 8];
#pragma unroll
        for (int nt = 0; nt < 4; ++nt)
            bfr[nt] = *(const bf16x8*)&Bs[coffB + (nw + nt * 16 + lk) * 32 + lq * 8];

        if (k0 + 32 < Kdim) {
            const int noffA = cur ? 0 : 2048;
            const int noffB = cur ? 0 : 4096;
            gload_lds16(agp  + k0 + 32, ad  + noffA);
            gload_lds16(bgp0 + k0 + 32, bd0 + noffB);
            gload_lds16(bgp1 + k0 + 32, bd1 + noffB);
        }

#pragma unroll
        for (int mt = 0; mt < 2; ++mt)
#pragma unroll
            for (int nt = 0; nt < 4; ++nt)
                acc[mt][nt] = __builtin_amdgcn_mfma_f32_16x16x32_bf16(bfr[nt], af[mt], acc[mt][nt], 0, 0, 0);

        __syncthreads();
        cur ^= 1;
    }

    float4 bv[4];
#pragma unroll
    for (int nt = 0; nt < 4; ++nt)
        bv[nt] = *(const float4*)(bias + n0 + nw + nt * 16 + lq * 4);
#pragma unroll
    for (int mt = 0; mt < 2; ++mt) {
        float* rowp = outp + (size_t)(m0 + mw + mt * 16 + lk) * Ndim + n0 + nw + lq * 4;
#pragma unroll
        for (int nt = 0; nt < 4; ++nt) {
            float4 v;
            v.x = acc[mt][nt][0] + bv[nt].x;
            v.y = acc[mt][nt][1] + bv[nt].y;
            v.z = acc[mt][nt][2] + bv[nt].z;
            v.w = acc[mt][nt][3] + bv[nt].w;
            *(float4*)(rowp + nt * 16) = v;
        }
    }
}

// ---------------------------------------------------------------------------
// MFMA flash attention v13 = v9 structure + STATIC-MAX softmax.
//  - v9 (best measured: 42.9us): 128-row q-tiles, 8 waves, K+V double-buffer,
//    one barrier/tile, K prefetch via gload_lds / V via regs pre-compute.
//  - Softmax is shift-invariant: exp2(S*SC - M0) with FIXED M0=16 is exact
//    (no overflow: needs S>800; underflow only for zero-contribution tails;
//    the common scale cancels in O = acc/l; bf16 precision is scale-inv).
//    Removes per tile: max tree, 2 shfl max hops, grow/corr branch, 16-elem
//    acc rescale, m_run, AND both l-sum shfl hops (deferred to epilogue).
//    No cross-lane ops left in the main loop.
// ---------------------------------------------------------------------------
constexpr int LDV = 136;            // Vt padded leading dim
constexpr float SC = 0.18033688f;   // 0.125 * log2(e)
constexpr float M0 = 16.0f;         // static softmax shift (exact, see above)

__global__ __launch_bounds__(512, 2)
void attn_mfma(const short* __restrict__ qkv, short* __restrict__ att)
{
    __shared__ __align__(16) short Ks[2][128 * 64];   // swizzled [key][d] 2x16 KB
    __shared__ __align__(16) short Vt[2][64 * LDV];   // permuted [d][key] 2x17 KB

    const int idx = blockIdx.x;
    const int xcd = idx & 7;
    const int j   = idx >> 3;                // 0..63
    const int bh  = xcd * 4 + (j & 3);
    const int s   = j >> 2;                  // 0..15
    const int qt  = (s < 8) ? s : (23 - s);  // pair (s,s+8): (qt+1)+(16-qt)=17
    const int b   = bh >> 4;
    const int h   = bh & 15;
    const int qbase = qt * 128;

    const int tid = threadIdx.x;
    const int w   = tid >> 6;                // 0..7
    const int l   = tid & 63;
    const int lk  = l & 15;
    const int lq  = l >> 4;

    const short* base = qkv + (size_t)b * T * 3072 + h * 64;

    // Q fragments (B-operand of S^T); lane owns q-row q_abs
    const int q_abs = qbase + w * 16 + lk;
    const short* qp = base + (size_t)q_abs * 3072 + lq * 8;
    const bf16x8 qf0 = *(const bf16x8*)qp;
    const bf16x8 qf1 = *(const bf16x8*)(qp + 32);

    f32x4 acc_o[4];
#pragma unroll
    for (int dt = 0; dt < 4; ++dt) acc_o[dt] = (f32x4){0.f, 0.f, 0.f, 0.f};
    float lacc = 0.f;                        // deferred per-lane l partial

    const int krow   = l >> 3;
    const int kcolsw = 8 * ((l & 7) ^ (l >> 3));
    const int swz    = lk & 7;

    const int kg   = tid & 31;
    const int vd0  = ((tid >> 5) & 7) * 8;
    const int pcol = ((kg & 24) | ((kg & 3) << 1) | ((kg >> 2) & 1)) * 4;

    const int nkt = qt + 1;

    bf16x8 vv[4];

    // --- prologue: stage tile 0 (full latency paid once) ---
    if (w < 4) {
#pragma unroll
        for (int rr = 0; rr < 4; ++rr) {
            const int g = w * 32 + rr * 8;
            gload_lds16(base + 1024 + (size_t)(g + krow) * 3072 + kcolsw, &Ks[0][g * 64]);
        }
    } else {
        const short* vp = base + 2048 + (size_t)(kg * 4) * 3072 + vd0;
#pragma unroll
        for (int kk = 0; kk < 4; ++kk)
            vv[kk] = *(const bf16x8*)(vp + (size_t)kk * 3072);
#pragma unroll
        for (int d = 0; d < 8; ++d) {
            short4 pk;
            pk.x = vv[0][d]; pk.y = vv[1][d]; pk.z = vv[2][d]; pk.w = vv[3][d];
            *(short4*)&Vt[0][(vd0 + d) * LDV + pcol] = pk;
        }
    }
    __syncthreads();

#pragma unroll 1
    for (int it = 0; it < nkt; ++it) {
        const int j0  = it * 128;
        const int buf = it & 1;
        const int nb  = buf ^ 1;

        // --- issue next-tile prefetch before compute (latency hides) ---
        if (it + 1 < nkt) {
            const int j1 = j0 + 128;
            if (w < 4) {
#pragma unroll
                for (int rr = 0; rr < 4; ++rr) {
                    const int g = w * 32 + rr * 8;
                    gload_lds16(base + 1024 + (size_t)(j1 + g + krow) * 3072 + kcolsw,
                                &Ks[nb][g * 64]);
                }
            } else {
                const short* vp = base + 2048 + (size_t)(j1 + kg * 4) * 3072 + vd0;
#pragma unroll
                for (int kk = 0; kk < 4; ++kk)
                    vv[kk] = *(const bf16x8*)(vp + (size_t)kk * 3072);
            }
        }

        // --- S^T = K Q^T: s4[kt][r] = S[key = j0 + kt*16 + lq*4 + r][q = lk] ---
        f32x4 s4[8];
        __builtin_amdgcn_s_setprio(1);
#pragma unroll
        for (int kt = 0; kt < 8; ++kt) {
            const int row = kt * 16 + lk;
            const bf16x8 kf0 = *(const bf16x8*)&Ks[buf][row * 64 + 8 * (lq ^ swz)];
            const bf16x8 kf1 = *(const bf16x8*)&Ks[buf][row * 64 + 8 * ((lq + 4) ^ swz)];
            f32x4 a = (f32x4){0.f, 0.f, 0.f, 0.f};
            a = __builtin_amdgcn_mfma_f32_16x16x32_bf16(kf0, qf0, a, 0, 0, 0);
            a = __builtin_amdgcn_mfma_f32_16x16x32_bf16(kf1, qf1, a, 0, 0, 0);
            s4[kt] = a;
        }
        __builtin_amdgcn_s_setprio(0);

        // --- causal mask (last tile only) ---
        if (it == nkt - 1) {
#pragma unroll
            for (int kt = 0; kt < 8; ++kt)
#pragma unroll
                for (int r = 0; r < 4; ++r)
                    if (j0 + kt * 16 + lq * 4 + r > q_abs) s4[kt][r] = -1e30f;
        }

        // --- static-max softmax: P = exp2(S*SC - M0); no cross-lane ops ---
#pragma unroll
        for (int kt = 0; kt < 8; ++kt)
#pragma unroll
            for (int r = 0; r < 4; ++r)
                s4[kt][r] = EXP2(fmaf(s4[kt][r], SC, -M0));

        float ts[8];
#pragma unroll
        for (int kt = 0; kt < 8; ++kt)
            ts[kt] = (s4[kt][0] + s4[kt][1]) + (s4[kt][2] + s4[kt][3]);
        lacc += ((ts[0] + ts[1]) + (ts[2] + ts[3]))
              + ((ts[4] + ts[5]) + (ts[6] + ts[7]));

        // --- pack P rows to dwords ---
        unsigned int d0[8], d1[8];
#pragma unroll
        for (int kt = 0; kt < 8; ++kt) {
            d0[kt] = (unsigned int)(unsigned short)f2bf(s4[kt][0])
                   | ((unsigned int)(unsigned short)f2bf(s4[kt][1]) << 16);
            d1[kt] = (unsigned int)(unsigned short)f2bf(s4[kt][2])
                   | ((unsigned int)(unsigned short)f2bf(s4[kt][3]) << 16);
        }

        // --- O^T += V^T P^T (no rescale needed: static shift) ---
        __builtin_amdgcn_s_setprio(1);
#pragma unroll
        for (int kc = 0; kc < 4; ++kc) {
            union { unsigned int u[4]; bf16x8 v; } up;
            up.u[0] = d0[kc * 2];
            up.u[1] = d1[kc * 2];
            up.u[2] = d0[kc * 2 + 1];
            up.u[3] = d1[kc * 2 + 1];
            const bf16x8 pf = up.v;
#pragma unroll
            for (int dt = 0; dt < 4; ++dt) {
                const bf16x8 vf = *(const bf16x8*)&Vt[buf][(dt * 16 + lk) * LDV + kc * 32 + lq * 8];
                acc_o[dt] = __builtin_amdgcn_mfma_f32_16x16x32_bf16(vf, pf, acc_o[dt], 0, 0, 0);
            }
        }
        __builtin_amdgcn_s_setprio(0);

        // --- write prefetched V into the spare buffer (after its readers) ---
        if (it + 1 < nkt && w >= 4) {
#pragma unroll
            for (int d = 0; d < 8; ++d) {
                short4 pk;
                pk.x = vv[0][d]; pk.y = vv[1][d]; pk.z = vv[2][d]; pk.w = vv[3][d];
                *(short4*)&Vt[nb][(vd0 + d) * LDV + pcol] = pk;
            }
        }

        __syncthreads();   // single barrier: drains K gloads + V writes, frees old bufs
    }

    // --- epilogue: reduce l across the 4 lq-lanes, then O = O^T/l ---
    float ls = lacc;
    ls += __shfl_xor(ls, 16);
    ls += __shfl_xor(ls, 32);
    const float inv = 1.f / ls;
    short* op = att + ((size_t)(b * T + q_abs)) * 1024 + h * 64;
#pragma unroll
    for (int dt = 0; dt < 4; ++dt) {
        short4 pk;
        pk.x = f2bf(acc_o[dt][0] * inv);
        pk.y = f2bf(acc_o[dt][1] * inv);
        pk.z = f2bf(acc_o[dt][2] * inv);
        pk.w = f2bf(acc_o[dt][3] * inv);
        *(short4*)(op + dt * 16 + lq * 4) = pk;
    }
}

// ---------------------------------------------------------------------------
extern "C" void kernel_launch(void* const* d_in, const int* in_sizes, int n_in,
                              void* d_out, int out_size, void* d_ws, size_t ws_size,
                              hipStream_t stream)
{
    const float* x      = (const float*)d_in[0];   // [B,T,C]
    const float* w_qkv  = (const float*)d_in[1];   // [C,3C]
    const float* b_qkv  = (const float*)d_in[2];   // [3C]
    const float* w_proj = (const float*)d_in[3];   // [C,C]
    const float* b_proj = (const float*)d_in[4];   // [C]
    float* out = (float*)d_out;                    // [B,T,C] fp32

    short* xb     = (short*)d_ws;                        //  8 MB
    short* wqkvt  = xb     + (size_t)M * C;              //  6 MB  [3072][1024]
    short* wprojt = wqkvt  + (size_t)NQKV * C;           //  2 MB  [1024][1024]
    short* qkvb   = wprojt + (size_t)C * C;              // 24 MB  [4096][3072]
    short* attb   = qkvb   + (size_t)M * NQKV;           //  8 MB  [4096][1024]

    prep_all<<<8192, 256, 0, stream>>>(x, xb, w_qkv, wqkvt, w_proj, wprojt);
    gemm_mfma<<<dim3(NQKV / 128, M / 128), 256, 0, stream>>>(xb, wqkvt, b_qkv, qkvb, NQKV, C);
    attn_mfma<<<512, 512, 0, stream>>>(qkvb, attb);
    gemm_mfma_proj<<<dim3(C / 128, M / 64), 256, 0, stream>>>(attb, wprojt, b_proj, out, C, C);
}